// Round 7
// baseline (4307.479 us; speedup 1.0000x reference)
//
#include <hip/hip_runtime.h>
#include <stdint.h>

typedef unsigned short u16;

#define T_ 1024

__device__ __forceinline__ float wred_sum(float v) {
    #pragma unroll
    for (int o = 32; o > 0; o >>= 1) v += __shfl_down(v, o, 64);
    return v;
}
__device__ __forceinline__ float wred_max(float v) {
    #pragma unroll
    for (int o = 32; o > 0; o >>= 1) v = fmaxf(v, __shfl_down(v, o, 64));
    return v;
}

// ============ plain fp32 GEMM: C[m,n] = sum_k A[m,k]*W[k,n] + bias[n] ============
template <int RELU>
__global__ __launch_bounds__(256) void gemm_f32(const float* __restrict__ A,
                                                const float* __restrict__ W,
                                                const float* __restrict__ bias,
                                                float* __restrict__ C,
                                                int M, int N, int K) {
    __shared__ float As_t[16][65];
    __shared__ float Ws[16][65];
    const int m0 = blockIdx.x * 64, n0 = blockIdx.y * 64;
    const int tid = threadIdx.x;
    const int tx = tid & 15, ty = tid >> 4;
    float acc[4][4];
    #pragma unroll
    for (int i = 0; i < 4; i++)
        #pragma unroll
        for (int j = 0; j < 4; j++) acc[i][j] = 0.f;

    for (int k0 = 0; k0 < K; k0 += 16) {
        #pragma unroll
        for (int e = tid; e < 1024; e += 256) {
            int m = e >> 4, kk = e & 15;
            As_t[kk][m] = A[(long)(m0 + m) * K + k0 + kk];
        }
        #pragma unroll
        for (int e = tid; e < 1024; e += 256) {
            int kk = e >> 6, n = e & 63;
            Ws[kk][n] = W[(long)(k0 + kk) * N + n0 + n];
        }
        __syncthreads();
        #pragma unroll
        for (int kk = 0; kk < 16; kk++) {
            float av[4], wv[4];
            #pragma unroll
            for (int i = 0; i < 4; i++) av[i] = As_t[kk][ty * 4 + i];
            #pragma unroll
            for (int j = 0; j < 4; j++) wv[j] = Ws[kk][tx * 4 + j];
            #pragma unroll
            for (int i = 0; i < 4; i++)
                #pragma unroll
                for (int j = 0; j < 4; j++) acc[i][j] += av[i] * wv[j];
        }
        __syncthreads();
    }
    #pragma unroll
    for (int i = 0; i < 4; i++)
        #pragma unroll
        for (int j = 0; j < 4; j++) {
            int n = n0 + tx * 4 + j;
            float v = acc[i][j] + bias[n];
            if (RELU) v = fmaxf(v, 0.f);
            C[(long)(m0 + ty * 4 + i) * N + n] = v;
        }
}

// ============ repack Q/K/V heads: Xp[sz][t][d] = {U|V}f[(b*T+t)*3072 + blk + h*64+d]
__global__ __launch_bounds__(256) void repack(const float* __restrict__ Uf,
                                              const float* __restrict__ Vf,
                                              float* __restrict__ Qp,
                                              float* __restrict__ Kp,
                                              float* __restrict__ Vp) {
    int t0 = blockIdx.x * 64;
    int sz = blockIdx.y, s = sz >> 5, z = sz & 31, b = z >> 4, h = z & 15;
    const float* basep = s ? Vf : Uf;
    int tid = threadIdx.x;
    for (int e = tid; e < 4096; e += 256) {
        int t = t0 + (e >> 6), d = e & 63;
        long row = (long)(b * T_ + t) * 3072 + h * 64 + d;
        long o = ((long)sz * 1024 + t) * 64 + d;
        Qp[o] = basep[row];
        Kp[o] = basep[row + 1024];
        Vp[o] = basep[row + 2048];
    }
}

// ============ R/S matrices: RS[idx][d1][d2] = sum_j mask[j]*K[j,d1]*Q[j,d2] ==========
// idx 0..31 = R (source = v-stream, aux_mask), idx 32..63 = S (u-stream, src_mask).
__global__ __launch_bounds__(256) void rs_f32(const float* __restrict__ Qp,
                                              const float* __restrict__ Kp,
                                              const int* __restrict__ smask,
                                              const int* __restrict__ amask,
                                              float* __restrict__ RS) {
    __shared__ float Ksh[8192];
    __shared__ float Qsh[8192];
    int idx = blockIdx.x;
    int srcsz = idx ^ 32;
    const int* mk = (idx < 32) ? amask : smask;
    int z = idx & 31, b = z >> 4;
    int j0 = blockIdx.y * 128;
    int tid = threadIdx.x;
    for (int e = tid; e < 8192; e += 256) {
        int j = e >> 6, d = e & 63;
        int jj = j0 + j;
        long o = ((long)srcsz * 1024 + jj) * 64 + d;
        int m = mk[b * T_ + jj];
        Ksh[e] = (m > 0) ? Kp[o] : 0.f;
        Qsh[e] = Qp[o];
    }
    __syncthreads();
    int d1 = tid >> 2, c0 = (tid & 3) * 16;
    float a[16];
    #pragma unroll
    for (int c = 0; c < 16; c++) a[c] = 0.f;
    for (int j = 0; j < 128; j++) {
        float kv = Ksh[j * 64 + d1];
        #pragma unroll
        for (int c = 0; c < 16; c++) a[c] += kv * Qsh[j * 64 + c0 + c];
    }
    float* out = RS + (long)idx * 4096 + d1 * 64 + c0;
    #pragma unroll
    for (int c = 0; c < 16; c++) atomicAdd(&out[c], a[c]);
}

// ============ Q' = (Q @ RS[sz]) / 64 ================================================
__global__ __launch_bounds__(256) void qprime_f32(const float* __restrict__ Qp,
                                                  const float* __restrict__ RS,
                                                  float* __restrict__ Qp2) {
    __shared__ float Rm[4096];
    int t0 = blockIdx.x * 128;
    int sz = blockIdx.y;
    int tid = threadIdx.x;
    for (int e = tid; e < 4096; e += 256) Rm[e] = RS[(long)sz * 4096 + e];
    __syncthreads();
    int r = tid >> 1, c0 = (tid & 1) * 32;
    int t = t0 + r;
    const float* q = Qp + ((long)sz * 1024 + t) * 64;
    float acc[32];
    #pragma unroll
    for (int c = 0; c < 32; c++) acc[c] = 0.f;
    for (int d1 = 0; d1 < 64; d1++) {
        float qv = q[d1];
        #pragma unroll
        for (int c = 0; c < 32; c++) acc[c] += qv * Rm[d1 * 64 + c0 + c];
    }
    float* out = Qp2 + ((long)sz * 1024 + t) * 64 + c0;
    #pragma unroll
    for (int c = 0; c < 32; c++) out[c] = acc[c] * (1.f / 64.f);
}

// ============ comb[zl][i][k] = mask[k] ? Q'[sz0+zl][i]·K[sz0+zl][k] : 0  ============
__global__ __launch_bounds__(256) void comb_f32(const float* __restrict__ Qp2,
                                                const float* __restrict__ Kp,
                                                float* __restrict__ comb,
                                                const int* __restrict__ mk,
                                                int sz0) {
    __shared__ float Qs[64][65];
    __shared__ float Ks2[64][65];
    int i0 = blockIdx.x * 64, k0 = blockIdx.y * 64, zl = blockIdx.z;
    int z = (sz0 + zl) & 31, b = z >> 4;
    int tid = threadIdx.x;
    for (int e = tid; e < 4096; e += 256) {
        int r = e >> 6, d = e & 63;
        Qs[r][d] = Qp2[((long)(sz0 + zl) * 1024 + i0 + r) * 64 + d];
        Ks2[r][d] = Kp[((long)(sz0 + zl) * 1024 + k0 + r) * 64 + d];
    }
    __syncthreads();
    int tx = tid & 15, ty = tid >> 4;
    float acc[4][4];
    #pragma unroll
    for (int i = 0; i < 4; i++)
        #pragma unroll
        for (int j = 0; j < 4; j++) acc[i][j] = 0.f;
    for (int d = 0; d < 64; d++) {
        float qv[4], kv[4];
        #pragma unroll
        for (int i = 0; i < 4; i++) qv[i] = Qs[ty * 4 + i][d];
        #pragma unroll
        for (int j = 0; j < 4; j++) kv[j] = Ks2[tx * 4 + j][d];
        #pragma unroll
        for (int i = 0; i < 4; i++)
            #pragma unroll
            for (int j = 0; j < 4; j++) acc[i][j] += qv[i] * kv[j];
    }
    #pragma unroll
    for (int i = 0; i < 4; i++)
        #pragma unroll
        for (int j = 0; j < 4; j++) {
            int col = k0 + tx * 4 + j;
            float v = (mk[b * T_ + col] > 0) ? acc[i][j] : 0.f;
            comb[((long)zl * 1024 + i0 + ty * 4 + i) * 1024 + col] = v;
        }
}

// ============ row softmax, fp32 in-place ============================================
__global__ __launch_bounds__(256) void softmax_f32(float* __restrict__ comb) {
    __shared__ float red[8];
    int row = blockIdx.x, zl = blockIdx.y;
    float* p = comb + ((long)zl * 1024 + row) * 1024;
    int tid = threadIdx.x, wave = tid >> 6, lane = tid & 63;
    float v0 = p[tid], v1 = p[tid + 256], v2 = p[tid + 512], v3 = p[tid + 768];
    float mx = fmaxf(fmaxf(v0, v1), fmaxf(v2, v3));
    mx = wred_max(mx);
    if (lane == 0) red[wave] = mx;
    __syncthreads();
    mx = fmaxf(fmaxf(red[0], red[1]), fmaxf(red[2], red[3]));
    v0 = __expf(v0 - mx); v1 = __expf(v1 - mx); v2 = __expf(v2 - mx); v3 = __expf(v3 - mx);
    float s = wred_sum(v0 + v1 + v2 + v3);
    if (lane == 0) red[4 + wave] = s;
    __syncthreads();
    s = red[4] + red[5] + red[6] + red[7];
    float inv = 1.f / s;
    p[tid] = v0 * inv;
    p[tid + 256] = v1 * inv;
    p[tid + 512] = v2 * inv;
    p[tid + 768] = v3 * inv;
}

// ============ PV: ctx[b*T+t][h*64+d] = sum_k att[zl][t][k] * Vp[sz0+zl][k][d] =======
__global__ __launch_bounds__(256) void pv_f32(const float* __restrict__ att,
                                              const float* __restrict__ Vp,
                                              float* __restrict__ ctx, int sz0) {
    __shared__ float Ps[64][65];
    __shared__ float Vs[64][65];
    int t0 = blockIdx.x * 64, zl = blockIdx.y;
    int z = (sz0 + zl) & 31, b = z >> 4, h = z & 15;
    int tid = threadIdx.x;
    int tx = tid & 15, ty = tid >> 4;
    float acc[4][4];
    #pragma unroll
    for (int i = 0; i < 4; i++)
        #pragma unroll
        for (int j = 0; j < 4; j++) acc[i][j] = 0.f;
    for (int k0 = 0; k0 < 1024; k0 += 64) {
        for (int e = tid; e < 4096; e += 256) {
            int r = e >> 6, c = e & 63;
            Ps[r][c] = att[((long)zl * 1024 + t0 + r) * 1024 + k0 + c];
            Vs[r][c] = Vp[((long)(sz0 + zl) * 1024 + k0 + r) * 64 + c];
        }
        __syncthreads();
        for (int kk = 0; kk < 64; kk++) {
            float pv[4], vv[4];
            #pragma unroll
            for (int i = 0; i < 4; i++) pv[i] = Ps[ty * 4 + i][kk];
            #pragma unroll
            for (int j = 0; j < 4; j++) vv[j] = Vs[kk][tx * 4 + j];
            #pragma unroll
            for (int i = 0; i < 4; i++)
                #pragma unroll
                for (int j = 0; j < 4; j++) acc[i][j] += pv[i] * vv[j];
        }
        __syncthreads();
    }
    #pragma unroll
    for (int i = 0; i < 4; i++)
        #pragma unroll
        for (int j = 0; j < 4; j++)
            ctx[(long)(b * T_ + t0 + ty * 4 + i) * 1024 + h * 64 + tx * 4 + j] = acc[i][j];
}

// ============ residual + LayerNorm (fp32 in, fp32 out) ==============================
__global__ __launch_bounds__(256) void ln_f32(const float* __restrict__ x,
                                              const float* __restrict__ y,
                                              const float* __restrict__ g,
                                              const float* __restrict__ be,
                                              float* __restrict__ out) {
    __shared__ float red[8];
    int row = blockIdx.x;
    long base = (long)row * 1024;
    int tid = threadIdx.x, wave = tid >> 6, lane = tid & 63;
    float v[4];
    #pragma unroll
    for (int i = 0; i < 4; i++) {
        int c = tid + i * 256;
        v[i] = x[base + c] + y[base + c];
    }
    float s = v[0] + v[1] + v[2] + v[3];
    float q = v[0] * v[0] + v[1] * v[1] + v[2] * v[2] + v[3] * v[3];
    s = wred_sum(s);
    q = wred_sum(q);
    if (lane == 0) { red[wave] = s; red[4 + wave] = q; }
    __syncthreads();
    s = red[0] + red[1] + red[2] + red[3];
    q = red[4] + red[5] + red[6] + red[7];
    float mean = s * (1.f / 1024.f);
    float var = q * (1.f / 1024.f) - mean * mean;
    float inv = rsqrtf(var + 1e-5f);
    #pragma unroll
    for (int i = 0; i < 4; i++) {
        int c = tid + i * 256;
        out[base + c] = (v[i] - mean) * inv * g[c] + be[c];
    }
}

extern "C" void kernel_launch(void* const* d_in, const int* in_sizes, int n_in,
                              void* d_out, int out_size, void* d_ws, size_t ws_size,
                              hipStream_t stream) {
    const float* src = (const float*)d_in[0];
    const float* aux = (const float*)d_in[1];
    const float* Wu = (const float*)d_in[2];
    const float* bu = (const float*)d_in[3];
    const float* Wv = (const float*)d_in[4];
    const float* bv = (const float*)d_in[5];
    const float* Wo = (const float*)d_in[6];
    const float* bo = (const float*)d_in[7];
    const float* W1 = (const float*)d_in[8];
    const float* b1 = (const float*)d_in[9];
    const float* W2 = (const float*)d_in[10];
    const float* b2 = (const float*)d_in[11];
    const float* g1 = (const float*)d_in[12];
    const float* be1 = (const float*)d_in[13];
    const float* g2 = (const float*)d_in[14];
    const float* be2 = (const float*)d_in[15];
    const int* src_mask = (const int*)d_in[16];
    const int* aux_mask = (const int*)d_in[17];

    // -------- workspace (~147 MiB peak, time-phased; layout proven safe R4/R5) ------
    char* w = (char*)d_ws;
    auto alloc = [&](size_t bytes) { char* p = w; w += (bytes + 255) & ~(size_t)255; return p; };
    // permanent
    float* RS = (float*)alloc(64L * 4096 * 4);
    float* Kp = (float*)alloc(64L * 1024 * 64 * 4);
    float* Vp = (float*)alloc(64L * 1024 * 64 * 4);
    float* Qp2 = (float*)alloc(64L * 1024 * 64 * 4);
    // scratch union (phase A: Uf,Vf,Qp ; phase B: comb,ctx,attn_s,o1s,hbuf,fbuf)
    char* scratch = (char*)alloc(100663296L);
    float* Uf = (float*)(scratch);
    float* Vf = (float*)(scratch + 25165824L);
    float* Qp = (float*)(scratch + 50331648L);
    float* comb = (float*)(scratch);
    float* ctx = (float*)(scratch + 33554432L);
    float* attn_s = (float*)(scratch + 41943040L);
    float* o1s = (float*)(scratch + 50331648L);
    float* hbuf = (float*)(scratch + 58720256L);
    float* fbuf = (float*)(scratch + 92274688L);

    // -------- phase A: QKV projections + head repack + R/S + Q' ---------------------
    gemm_f32<0><<<dim3(32, 48), 256, 0, stream>>>(src, Wu, bu, Uf, 2048, 3072, 1024);
    gemm_f32<0><<<dim3(32, 48), 256, 0, stream>>>(aux, Wv, bv, Vf, 2048, 3072, 1024);
    repack<<<dim3(16, 64), 256, 0, stream>>>(Uf, Vf, Qp, Kp, Vp);
    hipMemsetAsync(RS, 0, 64L * 4096 * 4, stream);
    rs_f32<<<dim3(64, 8), 256, 0, stream>>>(Qp, Kp, src_mask, aux_mask, RS);
    qprime_f32<<<dim3(8, 64), 256, 0, stream>>>(Qp, RS, Qp2);
    // phase A scratch (Uf/Vf/Qp) dead from here on

    // -------- phase B: attention (8-z chunks) + out-proj + LN + FFN + LN -----------
    for (int s = 0; s < 2; s++) {
        const int* mk = s ? aux_mask : src_mask;
        for (int c = 0; c < 4; c++) {
            int sz0 = s * 32 + c * 8;
            comb_f32<<<dim3(16, 16, 8), 256, 0, stream>>>(Qp2, Kp, comb, mk, sz0);
            softmax_f32<<<dim3(1024, 8), 256, 0, stream>>>(comb);
            pv_f32<<<dim3(16, 8), 256, 0, stream>>>(comb, Vp, ctx, sz0);
        }
        gemm_f32<0><<<dim3(32, 16), 256, 0, stream>>>(ctx, Wo, bo, attn_s, 2048, 1024, 1024);
        const float* x = s ? aux : src;
        ln_f32<<<2048, 256, 0, stream>>>(x, attn_s, g1, be1, o1s);
        gemm_f32<1><<<dim3(32, 64), 256, 0, stream>>>(o1s, W1, b1, hbuf, 2048, 4096, 1024);
        gemm_f32<0><<<dim3(32, 16), 256, 0, stream>>>(hbuf, W2, b2, fbuf, 2048, 1024, 4096);
        ln_f32<<<2048, 256, 0, stream>>>(o1s, fbuf, g2, be2,
                                         (float*)d_out + (long)s * 2097152);
    }
}

// Round 8
// 1132.411 us; speedup vs baseline: 3.8038x; 3.8038x over previous
//
#include <hip/hip_runtime.h>
#include <stdint.h>

typedef unsigned short u16;
typedef __attribute__((ext_vector_type(4))) float f32x4;
typedef __attribute__((ext_vector_type(8))) __bf16 bf16x8;

#define T_ 1024
#define D_ 1024
#define HD_ 64

__device__ __forceinline__ float b2f(u16 u) {
    union { unsigned int i; float f; } x; x.i = ((unsigned int)u) << 16; return x.f;
}
__device__ __forceinline__ u16 f2b(float f) {
    union { float f; unsigned int i; } x; x.f = f;
    unsigned int i = x.i;
    unsigned int r = (i >> 16) & 1;
    i += 0x7fffu + r;
    return (u16)(i >> 16);
}

// async global->LDS, 16B per lane; LDS dest is wave-uniform base + lane*16
__device__ __forceinline__ void gl2lds16(const void* g, void* l) {
    auto gp = (const __attribute__((address_space(1))) unsigned int*)(unsigned long long)(g);
    auto lp = (__attribute__((address_space(3))) unsigned int*)(unsigned int)(unsigned long long)(l);
    __builtin_amdgcn_global_load_lds(gp, lp, 16, 0, 0);
}

__device__ __forceinline__ float wred_sum(float v) {
    #pragma unroll
    for (int o = 32; o > 0; o >>= 1) v += __shfl_down(v, o, 64);
    return v;
}
__device__ __forceinline__ float wred_max(float v) {
    #pragma unroll
    for (int o = 32; o > 0; o >>= 1) v = fmaxf(v, __shfl_down(v, o, 64));
    return v;
}

// ---------------- f32 transpose + bf16 convert: out[c*R + r] = bf16(in[r*C + c]) ----
__global__ __launch_bounds__(256) void transpose_cvt(const float* __restrict__ in,
                                                     u16* __restrict__ out, int R, int C) {
    __shared__ float Ts[64][65];
    int c0 = blockIdx.x * 64, r0 = blockIdx.y * 64;
    int tid = threadIdx.x, tx = tid & 63, ty = tid >> 6;
    #pragma unroll
    for (int i = ty; i < 64; i += 4) Ts[i][tx] = in[(long)(r0 + i) * C + c0 + tx];
    __syncthreads();
    #pragma unroll
    for (int i = ty; i < 64; i += 4)
        out[(long)(c0 + i) * R + r0 + tx] = f2b(Ts[tx][i]);
}

// ---- f32 transpose + hi/lo split: W[R,C] -> out[C, 3R] = [hi | hi | lo] ------------
__global__ __launch_bounds__(256) void transpose_split(const float* __restrict__ in,
                                                       u16* __restrict__ out, int R, int C) {
    __shared__ float Ts[64][65];
    int c0 = blockIdx.x * 64, r0 = blockIdx.y * 64;
    int tid = threadIdx.x, tx = tid & 63, ty = tid >> 6;
    #pragma unroll
    for (int i = ty; i < 64; i += 4) Ts[i][tx] = in[(long)(r0 + i) * C + c0 + tx];
    __syncthreads();
    #pragma unroll
    for (int i = ty; i < 64; i += 4) {
        float v = Ts[tx][i];
        u16 hi = f2b(v);
        u16 lo = f2b(v - b2f(hi));
        long base = (long)(c0 + i) * (3 * R) + r0 + tx;
        out[base] = hi;
        out[base + R] = hi;
        out[base + 2 * R] = lo;
    }
}

// ---- f32 rowwise hi/lo split: X[M,1024] -> out[M, 3072] = [hi | lo | hi] -----------
__global__ __launch_bounds__(256) void split_rows(const float* __restrict__ in,
                                                  u16* __restrict__ out) {
    long row = blockIdx.x;
    int tid = threadIdx.x;
    #pragma unroll
    for (int k = 0; k < 4; k++) {
        int c = tid + k * 256;
        float v = in[row * 1024 + c];
        u16 hi = f2b(v);
        u16 lo = f2b(v - b2f(hi));
        out[row * 3072 + c] = hi;
        out[row * 3072 + 1024 + c] = lo;
        out[row * 3072 + 2048 + c] = hi;
    }
}

// ---------------- m97-style 128x128 BT GEMM: C = A[M,K] * B[N,K]^T ----------------
enum { EPI_F32_BIAS = 0, EPI_BF16_BIAS = 1, EPI_BF16_BIAS_RELU = 2, EPI_COMB = 3 };

template <int EPI>
__global__ __launch_bounds__(256) void gemm128(
    const u16* __restrict__ A, const u16* __restrict__ B, void* __restrict__ C,
    const float* __restrict__ bias, const int* __restrict__ mask,
    int M, int N, int K, int lda, int ldb, int ldc,
    long sAz, long sBz, long sCz, int zofs) {
    __shared__ u16 As[128 * 32];
    __shared__ u16 Bs[128 * 32];
    const int tid = threadIdx.x, wave = tid >> 6, lane = tid & 63;
    const int m0 = blockIdx.x * 128, n0 = blockIdx.y * 128;
    const int zl = blockIdx.z, z = zl + zofs;
    const u16* Ab = A + (long)z * sAz;
    const u16* Bb = B + (long)z * sBz;
    const int srow = lane >> 2, scol = (lane & 3) * 8;
    f32x4 acc[4][4];
    #pragma unroll
    for (int i = 0; i < 4; i++)
        #pragma unroll
        for (int j = 0; j < 4; j++) acc[i][j] = (f32x4){0.f, 0.f, 0.f, 0.f};
    const int wm = (wave >> 1) * 64, wn = (wave & 1) * 64;
    const int fr = lane & 15, fk = (lane >> 4) * 8;

    for (int k0 = 0; k0 < K; k0 += 32) {
        #pragma unroll
        for (int t = 0; t < 2; t++) {
            int rb = wave * 32 + t * 16;
            gl2lds16(Ab + (long)(m0 + rb + srow) * lda + k0 + scol, &As[rb * 32]);
            gl2lds16(Bb + (long)(n0 + rb + srow) * ldb + k0 + scol, &Bs[rb * 32]);
        }
        __syncthreads();
        bf16x8 af[4], bv[4];
        #pragma unroll
        for (int i = 0; i < 4; i++) af[i] = *(const bf16x8*)&As[(wm + i * 16 + fr) * 32 + fk];
        #pragma unroll
        for (int j = 0; j < 4; j++) bv[j] = *(const bf16x8*)&Bs[(wn + j * 16 + fr) * 32 + fk];
        #pragma unroll
        for (int i = 0; i < 4; i++)
            #pragma unroll
            for (int j = 0; j < 4; j++)
                acc[i][j] = __builtin_amdgcn_mfma_f32_16x16x32_bf16(af[i], bv[j], acc[i][j], 0, 0, 0);
        __syncthreads();
    }
    const int er = (lane >> 4) * 4, ec = lane & 15;
    #pragma unroll
    for (int i = 0; i < 4; i++)
        #pragma unroll
        for (int j = 0; j < 4; j++)
            #pragma unroll
            for (int r = 0; r < 4; r++) {
                const int gm = m0 + wm + i * 16 + er + r;
                const int gn = n0 + wn + j * 16 + ec;
                const float v = acc[i][j][r];
                if constexpr (EPI == EPI_COMB) {
                    ((float*)C)[(long)zl * sCz + (long)gm * ldc + gn] =
                        (mask[(z >> 4) * T_ + gn] > 0) ? v : 0.0f;
                } else if constexpr (EPI == EPI_F32_BIAS) {
                    ((float*)C)[(long)gm * ldc + gn] = v + bias[gn];
                } else if constexpr (EPI == EPI_BF16_BIAS) {
                    ((u16*)C)[(long)gm * ldc + gn] = f2b(v + bias[gn]);
                } else {
                    ((u16*)C)[(long)gm * ldc + gn] = f2b(fmaxf(v + bias[gn], 0.0f));
                }
            }
}

// ---------------- repack V^T: Vt[s,z,d,t] = U/Vf[b*T+t, 2048+h*64+d] ----------------
__global__ __launch_bounds__(256) void repack_vt(const float* __restrict__ Uf,
                                                 const float* __restrict__ Vf,
                                                 u16* __restrict__ Vt) {
    __shared__ u16 Ts[64][65];
    int tid = threadIdx.x, tx = tid & 63, ty = tid >> 6;
    int t0 = blockIdx.x * 64;
    int sz = blockIdx.y, s = sz >> 5, z = sz & 31, b = z >> 4, h = z & 15;
    const float* srcp = s ? Vf : Uf;
    #pragma unroll
    for (int i = ty; i < 64; i += 4)
        Ts[i][tx] = f2b(srcp[(long)(b * T_ + t0 + i) * 3072 + 2048 + h * 64 + tx]);
    __syncthreads();
    u16* dst = Vt + (long)sz * HD_ * T_;
    #pragma unroll
    for (int i = ty; i < 64; i += 4) dst[(long)i * T_ + t0 + tx] = Ts[tx][i];
}

// ---------------- R/S: RS[idx] = sum_j mask[j]*k[j,d1]*q[j,d2] (fp32, validated) ----
__global__ __launch_bounds__(256) void rs_kernel(const float* __restrict__ Uf,
                                                 const float* __restrict__ Vf,
                                                 const int* __restrict__ smask,
                                                 const int* __restrict__ amask,
                                                 float* __restrict__ RS) {
    __shared__ float Ksh[128 * 64];
    __shared__ float Qsh[128 * 64];
    int idx = blockIdx.x;
    int mat = idx >> 5, z = idx & 31, b = z >> 4, h = z & 15;
    int j0 = blockIdx.y * 128;
    const float* base = mat ? Uf : Vf;
    const int* mk = mat ? smask : amask;
    int tid = threadIdx.x;
    for (int ii = tid; ii < 8192; ii += 256) {
        int j = ii >> 6, d = ii & 63;
        long row = (long)(b * T_ + j0 + j) * 3072 + h * 64;
        int m = mk[b * T_ + j0 + j];
        Ksh[ii] = (m > 0) ? base[row + 1024 + d] : 0.f;
        Qsh[ii] = base[row + d];
    }
    __syncthreads();
    int d1 = tid >> 2, c0 = (tid & 3) * 16;
    float a[16];
    #pragma unroll
    for (int c = 0; c < 16; c++) a[c] = 0.f;
    for (int j = 0; j < 128; j++) {
        float kv = Ksh[j * 64 + d1];
        #pragma unroll
        for (int c = 0; c < 16; c++) a[c] += kv * Qsh[j * 64 + c0 + c];
    }
    float* out = RS + (long)idx * 4096 + d1 * 64 + c0;
    #pragma unroll
    for (int c = 0; c < 16; c++) atomicAdd(&out[c], a[c]);
}

// ---------------- Q' = (Q @ R)/64, hi/lo split to [qhi|qlo|qhi] (192) ----------------
__global__ __launch_bounds__(256) void qprime(const float* __restrict__ Uf,
                                              const float* __restrict__ Vf,
                                              const float* __restrict__ RS,
                                              u16* __restrict__ Qs) {
    __shared__ float Rm[4096];
    int t0 = blockIdx.x * 128;
    int sz = blockIdx.y, s = sz >> 5, z = sz & 31, b = z >> 4, h = z & 15;
    const float* Qf = s ? Vf : Uf;
    const float* mat = RS + (long)(s * 32 + z) * 4096;
    int tid = threadIdx.x;
    for (int ii = tid; ii < 4096; ii += 256) Rm[ii] = mat[ii];
    __syncthreads();
    int r = tid >> 1, c0 = (tid & 1) * 32;
    long qrow = (long)(b * T_ + t0 + r) * 3072 + h * 64;
    float acc[32];
    #pragma unroll
    for (int c = 0; c < 32; c++) acc[c] = 0.f;
    for (int d1 = 0; d1 < 64; d1++) {
        float q = Qf[qrow + d1];
        #pragma unroll
        for (int c = 0; c < 32; c++) acc[c] += q * Rm[d1 * 64 + c0 + c];
    }
    u16* out = Qs + ((long)sz * T_ + (t0 + r)) * 192;
    #pragma unroll
    for (int c = 0; c < 32; c++) {
        float x = acc[c] * (1.f / 64.f);
        u16 hi = f2b(x);
        u16 lo = f2b(x - b2f(hi));
        out[c0 + c] = hi;
        out[64 + c0 + c] = lo;
        out[128 + c0 + c] = hi;
    }
}

// ---------------- K split to [khi|khi|klo] (192) ----------------
__global__ __launch_bounds__(256) void ksplit(const float* __restrict__ Uf,
                                              const float* __restrict__ Vf,
                                              u16* __restrict__ Ks) {
    int t0 = blockIdx.x * 128;
    int sz = blockIdx.y, s = sz >> 5, z = sz & 31, b = z >> 4, h = z & 15;
    const float* Kf = s ? Vf : Uf;
    int tid = threadIdx.x;
    int r = tid >> 1, c0 = (tid & 1) * 32;
    long krow = (long)(b * T_ + t0 + r) * 3072 + 1024 + h * 64;
    u16* out = Ks + ((long)sz * T_ + (t0 + r)) * 192;
    #pragma unroll
    for (int c = 0; c < 32; c++) {
        float x = Kf[krow + c0 + c];
        u16 hi = f2b(x);
        u16 lo = f2b(x - b2f(hi));
        out[c0 + c] = hi;
        out[64 + c0 + c] = hi;
        out[128 + c0 + c] = lo;
    }
}

// ---------------- row softmax: fp32 comb -> bf16 att ----------------
__global__ __launch_bounds__(256) void softmax_rows(const float* __restrict__ comb,
                                                    u16* __restrict__ att) {
    __shared__ float red[8];
    int row = blockIdx.x, zl = blockIdx.y;
    const float* src = comb + ((long)zl * T_ + row) * T_;
    u16* dst = att + ((long)zl * T_ + row) * T_;
    int tid = threadIdx.x, wave = tid >> 6, lane = tid & 63;
    float v0 = src[tid], v1 = src[tid + 256], v2 = src[tid + 512], v3 = src[tid + 768];
    float mx = fmaxf(fmaxf(v0, v1), fmaxf(v2, v3));
    mx = wred_max(mx);
    if (lane == 0) red[wave] = mx;
    __syncthreads();
    mx = fmaxf(fmaxf(red[0], red[1]), fmaxf(red[2], red[3]));
    v0 = __expf(v0 - mx); v1 = __expf(v1 - mx); v2 = __expf(v2 - mx); v3 = __expf(v3 - mx);
    float s = wred_sum(v0 + v1 + v2 + v3);
    if (lane == 0) red[4 + wave] = s;
    __syncthreads();
    s = red[4] + red[5] + red[6] + red[7];
    float inv = 1.f / s;
    dst[tid] = f2b(v0 * inv);
    dst[tid + 256] = f2b(v1 * inv);
    dst[tid + 512] = f2b(v2 * inv);
    dst[tid + 768] = f2b(v3 * inv);
}

// ---------------- PV: ctx[b*T+t, h*64+d] = att[zl] @ Vt[z]^T  (128x64 tile) ----------
__global__ __launch_bounds__(256) void attn_pv(const u16* __restrict__ att,
                                               const u16* __restrict__ Vt,
                                               u16* __restrict__ ctx, int zofs) {
    __shared__ u16 As[128 * 32];
    __shared__ u16 Bs[64 * 32];
    int tid = threadIdx.x, wave = tid >> 6, lane = tid & 63;
    int m0 = blockIdx.x * 128;
    int zl = blockIdx.y, z = zl + zofs, b = z >> 4, h = z & 15;
    const u16* Ab = att + (long)zl * T_ * T_;
    const u16* Bb = Vt + (long)z * HD_ * T_;
    int srow = lane >> 2, scol = (lane & 3) * 8;
    f32x4 acc[2][4];
    #pragma unroll
    for (int i = 0; i < 2; i++)
        #pragma unroll
        for (int j = 0; j < 4; j++) acc[i][j] = (f32x4){0.f, 0.f, 0.f, 0.f};
    int fr = lane & 15, fk = (lane >> 4) * 8;
    for (int k0 = 0; k0 < T_; k0 += 32) {
        #pragma unroll
        for (int t = 0; t < 2; t++) {
            int rb = wave * 32 + t * 16;
            gl2lds16(Ab + (long)(m0 + rb + srow) * T_ + k0 + scol, &As[rb * 32]);
        }
        int rbb = wave * 16;
        gl2lds16(Bb + (long)(rbb + srow) * T_ + k0 + scol, &Bs[rbb * 32]);
        __syncthreads();
        bf16x8 af[2], bv[4];
        #pragma unroll
        for (int i = 0; i < 2; i++) af[i] = *(const bf16x8*)&As[(wave * 32 + i * 16 + fr) * 32 + fk];
        #pragma unroll
        for (int j = 0; j < 4; j++) bv[j] = *(const bf16x8*)&Bs[(j * 16 + fr) * 32 + fk];
        #pragma unroll
        for (int i = 0; i < 2; i++)
            #pragma unroll
            for (int j = 0; j < 4; j++)
                acc[i][j] = __builtin_amdgcn_mfma_f32_16x16x32_bf16(af[i], bv[j], acc[i][j], 0, 0, 0);
        __syncthreads();
    }
    int er = (lane >> 4) * 4, ec = lane & 15;
    #pragma unroll
    for (int i = 0; i < 2; i++)
        #pragma unroll
        for (int j = 0; j < 4; j++)
            #pragma unroll
            for (int r = 0; r < 4; r++) {
                int t = m0 + wave * 32 + i * 16 + er + r;
                int d = j * 16 + ec;
                ctx[(long)(b * T_ + t) * D_ + h * 64 + d] = f2b(acc[i][j][r]);
            }
}

// ------- fused residual-add + LayerNorm: x f32-or-bf16, y bf16, out bf16-or-f32 -----
template <bool XF32, bool OUTF32>
__global__ __launch_bounds__(256) void ln_fused(const void* __restrict__ xp,
                                                const u16* __restrict__ y,
                                                const float* __restrict__ g,
                                                const float* __restrict__ be,
                                                void* __restrict__ out) {
    __shared__ float red[8];
    int row = blockIdx.x;
    long base = (long)row * 1024;
    int tid = threadIdx.x, wave = tid >> 6, lane = tid & 63;
    float v[4];
    #pragma unroll
    for (int i = 0; i < 4; i++) {
        int c = tid + i * 256;
        float xv = XF32 ? ((const float*)xp)[base + c] : b2f(((const u16*)xp)[base + c]);
        v[i] = xv + b2f(y[base + c]);
    }
    float s = v[0] + v[1] + v[2] + v[3];
    float q = v[0] * v[0] + v[1] * v[1] + v[2] * v[2] + v[3] * v[3];
    s = wred_sum(s);
    q = wred_sum(q);
    if (lane == 0) { red[wave] = s; red[4 + wave] = q; }
    __syncthreads();
    s = red[0] + red[1] + red[2] + red[3];
    q = red[4] + red[5] + red[6] + red[7];
    float mean = s * (1.f / 1024.f);
    float var = q * (1.f / 1024.f) - mean * mean;
    float inv = rsqrtf(var + 1e-5f);
    #pragma unroll
    for (int i = 0; i < 4; i++) {
        int c = tid + i * 256;
        float o = (v[i] - mean) * inv * g[c] + be[c];
        if (OUTF32) ((float*)out)[base + c] = o;
        else ((u16*)out)[base + c] = f2b(o);
    }
}

extern "C" void kernel_launch(void* const* d_in, const int* in_sizes, int n_in,
                              void* d_out, int out_size, void* d_ws, size_t ws_size,
                              hipStream_t stream) {
    const float* src = (const float*)d_in[0];
    const float* aux = (const float*)d_in[1];
    const float* Wu = (const float*)d_in[2];
    const float* bu = (const float*)d_in[3];
    const float* Wv = (const float*)d_in[4];
    const float* bv = (const float*)d_in[5];
    const float* Wo = (const float*)d_in[6];
    const float* bo = (const float*)d_in[7];
    const float* W1 = (const float*)d_in[8];
    const float* b1 = (const float*)d_in[9];
    const float* W2 = (const float*)d_in[10];
    const float* b2 = (const float*)d_in[11];
    const float* g1 = (const float*)d_in[12];
    const float* be1 = (const float*)d_in[13];
    const float* g2 = (const float*)d_in[14];
    const float* be2 = (const float*)d_in[15];
    const int* src_mask = (const int*)d_in[16];
    const int* aux_mask = (const int*)d_in[17];

    // -------- workspace (~159 MiB peak, time-phased; proven safe in R2/R7) ----------
    char* w = (char*)d_ws;
    auto alloc = [&](size_t bytes) { char* p = w; w += (bytes + 255) & ~(size_t)255; return p; };
    // permanent (~75 MiB)
    u16* WoT = (u16*)alloc(1024L * 1024 * 2);
    u16* W1T = (u16*)alloc(4096L * 1024 * 2);
    u16* W2T = (u16*)alloc(1024L * 4096 * 2);
    u16* Vt  = (u16*)alloc(64L * 64 * 1024 * 2);
    float* RS = (float*)alloc(64L * 4096 * 4);
    u16* Qs = (u16*)alloc(64L * 1024 * 192 * 2);
    u16* Ks = (u16*)alloc(64L * 1024 * 192 * 2);
    // scratch union: 84 MiB, two time-phases
    char* scratch = (char*)alloc(84L * 1024 * 1024);
    // phase A: WS (split weight, reused u then v), As_ (split activ.), Uf, Vf
    u16* WS  = (u16*)(scratch);                        // 18874368
    u16* As_ = (u16*)(scratch + 18874368L);            // 12582912
    float* Uf = (float*)(scratch + 31457280L);         // 25165824
    float* Vf = (float*)(scratch + 56623104L);         // 25165824 (ends 81788928)
    // phase B: comb (8 z-slices), att, ctx, attn_s, o1s, hbuf, fbuf
    float* comb = (float*)(scratch);                   // 33554432
    u16* att    = (u16*)(scratch + 33554432L);         // 16777216
    u16* ctx    = (u16*)(scratch + 50331648L);         // 4194304
    u16* attn_s = (u16*)(scratch + 54525952L);         // 4194304
    u16* o1s    = (u16*)(scratch + 58720256L);         // 4194304
    u16* hbuf   = (u16*)(scratch + 62914560L);         // 16777216
    u16* fbuf   = (u16*)(scratch + 79691776L);         // 4194304 (ends 83886080)

    // -------- phase A: weight prep + hi/lo QKV projections + R/S + Q'/K splits ------
    transpose_cvt<<<dim3(16, 16), 256, 0, stream>>>(Wo, WoT, 1024, 1024);
    transpose_cvt<<<dim3(64, 16), 256, 0, stream>>>(W1, W1T, 1024, 4096);
    transpose_cvt<<<dim3(16, 64), 256, 0, stream>>>(W2, W2T, 4096, 1024);

    // Uf = [src_hi|src_lo|src_hi] @ [Wu_hi|Wu_hi|Wu_lo]^T + bu  (fp32 accumulate)
    transpose_split<<<dim3(48, 16), 256, 0, stream>>>(Wu, WS, 1024, 3072);
    split_rows<<<2048, 256, 0, stream>>>(src, As_);
    gemm128<EPI_F32_BIAS><<<dim3(16, 24, 1), 256, 0, stream>>>(
        As_, WS, Uf, bu, nullptr, 2048, 3072, 3072, 3072, 3072, 3072, 0, 0, 0, 0);
    transpose_split<<<dim3(48, 16), 256, 0, stream>>>(Wv, WS, 1024, 3072);
    split_rows<<<2048, 256, 0, stream>>>(aux, As_);
    gemm128<EPI_F32_BIAS><<<dim3(16, 24, 1), 256, 0, stream>>>(
        As_, WS, Vf, bv, nullptr, 2048, 3072, 3072, 3072, 3072, 3072, 0, 0, 0, 0);

    repack_vt<<<dim3(16, 64), 256, 0, stream>>>(Uf, Vf, Vt);
    hipMemsetAsync(RS, 0, 64L * 4096 * 4, stream);
    rs_kernel<<<dim3(64, 8), 256, 0, stream>>>(Uf, Vf, src_mask, aux_mask, RS);
    qprime<<<dim3(8, 64), 256, 0, stream>>>(Uf, Vf, RS, Qs);
    ksplit<<<dim3(8, 64), 256, 0, stream>>>(Uf, Vf, Ks);
    // ---- phase A scratch (WS/As_/Uf/Vf) dead; phase B overlays ----------------------

    for (int s = 0; s < 2; s++) {
        const int* mk = s ? aux_mask : src_mask;
        const u16* Qsb = Qs + (long)s * 32 * 1024 * 192;
        const u16* Ksb = Ks + (long)s * 32 * 1024 * 192;
        for (int c = 0; c < 4; c++) {
            int zofs = c * 8;
            gemm128<EPI_COMB><<<dim3(8, 8, 8), 256, 0, stream>>>(
                Qsb, Ksb, comb, nullptr, mk, 1024, 1024, 192, 192, 192, 1024,
                192L * 1024, 192L * 1024, 1024L * 1024, zofs);
            softmax_rows<<<dim3(1024, 8), 256, 0, stream>>>(comb, att);
            attn_pv<<<dim3(8, 8), 256, 0, stream>>>(att, Vt + (long)s * 32 * 64 * 1024, ctx, zofs);
        }
        gemm128<EPI_BF16_BIAS><<<dim3(16, 8, 1), 256, 0, stream>>>(
            ctx, WoT, attn_s, bo, nullptr, 2048, 1024, 1024, 1024, 1024, 1024, 0, 0, 0, 0);
        const float* x = s ? aux : src;
        ln_fused<true, false><<<2048, 256, 0, stream>>>(x, attn_s, g1, be1, o1s);
        gemm128<EPI_BF16_BIAS_RELU><<<dim3(16, 32, 1), 256, 0, stream>>>(
            o1s, W1T, hbuf, b1, nullptr, 2048, 4096, 1024, 1024, 1024, 4096, 0, 0, 0, 0);
        gemm128<EPI_BF16_BIAS><<<dim3(16, 8, 1), 256, 0, stream>>>(
            hbuf, W2T, fbuf, b2, nullptr, 2048, 1024, 4096, 4096, 4096, 1024, 0, 0, 0, 0);
        ln_fused<false, true><<<2048, 256, 0, stream>>>(o1s, fbuf, g2, be2,
                                                        (float*)d_out + (long)s * 2097152);
    }
}

// Round 9
// 934.624 us; speedup vs baseline: 4.6088x; 1.2116x over previous
//
#include <hip/hip_runtime.h>
#include <stdint.h>

typedef unsigned short u16;
typedef __attribute__((ext_vector_type(4))) float f32x4;
typedef __attribute__((ext_vector_type(8))) __bf16 bf16x8;

#define T_ 1024
#define D_ 1024
#define HD_ 64

__device__ __forceinline__ float b2f(u16 u) {
    union { unsigned int i; float f; } x; x.i = ((unsigned int)u) << 16; return x.f;
}
__device__ __forceinline__ u16 f2b(float f) {
    union { float f; unsigned int i; } x; x.f = f;
    unsigned int i = x.i;
    unsigned int r = (i >> 16) & 1;
    i += 0x7fffu + r;
    return (u16)(i >> 16);
}

// async global->LDS, 16B per lane; LDS dest is wave-uniform base + lane*16
__device__ __forceinline__ void gl2lds16(const void* g, void* l) {
    auto gp = (const __attribute__((address_space(1))) unsigned int*)(unsigned long long)(g);
    auto lp = (__attribute__((address_space(3))) unsigned int*)(unsigned int)(unsigned long long)(l);
    __builtin_amdgcn_global_load_lds(gp, lp, 16, 0, 0);
}

__device__ __forceinline__ float wred_sum(float v) {
    #pragma unroll
    for (int o = 32; o > 0; o >>= 1) v += __shfl_down(v, o, 64);
    return v;
}
__device__ __forceinline__ float wred_max(float v) {
    #pragma unroll
    for (int o = 32; o > 0; o >>= 1) v = fmaxf(v, __shfl_down(v, o, 64));
    return v;
}

// ---------------- f32 transpose + bf16 convert: out[c*R + r] = bf16(in[r*C + c]) ----
__global__ __launch_bounds__(256) void transpose_cvt(const float* __restrict__ in,
                                                     u16* __restrict__ out, int R, int C) {
    __shared__ float Ts[64][65];
    int c0 = blockIdx.x * 64, r0 = blockIdx.y * 64;
    int tid = threadIdx.x, tx = tid & 63, ty = tid >> 6;
    #pragma unroll
    for (int i = ty; i < 64; i += 4) Ts[i][tx] = in[(long)(r0 + i) * C + c0 + tx];
    __syncthreads();
    #pragma unroll
    for (int i = ty; i < 64; i += 4)
        out[(long)(c0 + i) * R + r0 + tx] = f2b(Ts[tx][i]);
}

// ---- f32 transpose + hi/lo split: W[R,C] -> out[C, 3R] = [hi | hi | lo] ------------
__global__ __launch_bounds__(256) void transpose_split(const float* __restrict__ in,
                                                       u16* __restrict__ out, int R, int C) {
    __shared__ float Ts[64][65];
    int c0 = blockIdx.x * 64, r0 = blockIdx.y * 64;
    int tid = threadIdx.x, tx = tid & 63, ty = tid >> 6;
    #pragma unroll
    for (int i = ty; i < 64; i += 4) Ts[i][tx] = in[(long)(r0 + i) * C + c0 + tx];
    __syncthreads();
    #pragma unroll
    for (int i = ty; i < 64; i += 4) {
        float v = Ts[tx][i];
        u16 hi = f2b(v);
        u16 lo = f2b(v - b2f(hi));
        long base = (long)(c0 + i) * (3 * R) + r0 + tx;
        out[base] = hi;
        out[base + R] = hi;
        out[base + 2 * R] = lo;
    }
}

// ---- f32 rowwise hi/lo split: X[M,1024] -> out[M, 3072] = [hi | lo | hi] -----------
__global__ __launch_bounds__(256) void split_rows(const float* __restrict__ in,
                                                  u16* __restrict__ out) {
    long row = blockIdx.x;
    int tid = threadIdx.x;
    #pragma unroll
    for (int k = 0; k < 4; k++) {
        int c = tid + k * 256;
        float v = in[row * 1024 + c];
        u16 hi = f2b(v);
        u16 lo = f2b(v - b2f(hi));
        out[row * 3072 + c] = hi;
        out[row * 3072 + 1024 + c] = lo;
        out[row * 3072 + 2048 + c] = hi;
    }
}

// ---------------- m97-style BT GEMM: C = A[M,K] * B[N,K]^T, 128 x BN tile ----------
enum { EPI_F32_BIAS = 0, EPI_BF16_BIAS = 1, EPI_BF16_BIAS_RELU = 2, EPI_COMB = 3 };

template <int EPI, int BN>
__global__ __launch_bounds__(256) void gemm128(
    const u16* __restrict__ A, const u16* __restrict__ B, void* __restrict__ C,
    const float* __restrict__ bias, const int* __restrict__ mask,
    int M, int N, int K, int lda, int ldb, int ldc,
    long sAz, long sBz, long sCz, int zofs) {
    __shared__ u16 As[128 * 32];
    __shared__ u16 Bs[BN * 32];
    const int tid = threadIdx.x, wave = tid >> 6, lane = tid & 63;
    const int m0 = blockIdx.x * 128, n0 = blockIdx.y * BN;
    const int zl = blockIdx.z, z = zl + zofs;
    const u16* Ab = A + (long)z * sAz;
    const u16* Bb = B + (long)z * sBz;
    const int srow = lane >> 2, scol = (lane & 3) * 8;
    constexpr int IT = (BN == 128) ? 4 : 2;
    f32x4 acc[IT][4];
    #pragma unroll
    for (int i = 0; i < IT; i++)
        #pragma unroll
        for (int j = 0; j < 4; j++) acc[i][j] = (f32x4){0.f, 0.f, 0.f, 0.f};
    const int wm = (BN == 128) ? (wave >> 1) * 64 : wave * 32;
    const int wn = (BN == 128) ? (wave & 1) * 64 : 0;
    const int fr = lane & 15, fk = (lane >> 4) * 8;

    for (int k0 = 0; k0 < K; k0 += 32) {
        #pragma unroll
        for (int t = 0; t < 2; t++) {
            int rb = wave * 32 + t * 16;
            gl2lds16(Ab + (long)(m0 + rb + srow) * lda + k0 + scol, &As[rb * 32]);
        }
        if (BN == 128) {
            #pragma unroll
            for (int t = 0; t < 2; t++) {
                int rb = wave * 32 + t * 16;
                gl2lds16(Bb + (long)(n0 + rb + srow) * ldb + k0 + scol, &Bs[rb * 32]);
            }
        } else {
            int rb = wave * 16;
            gl2lds16(Bb + (long)(n0 + rb + srow) * ldb + k0 + scol, &Bs[rb * 32]);
        }
        __syncthreads();
        bf16x8 af[IT], bv[4];
        #pragma unroll
        for (int i = 0; i < IT; i++) af[i] = *(const bf16x8*)&As[(wm + i * 16 + fr) * 32 + fk];
        #pragma unroll
        for (int j = 0; j < 4; j++) bv[j] = *(const bf16x8*)&Bs[(wn + j * 16 + fr) * 32 + fk];
        #pragma unroll
        for (int i = 0; i < IT; i++)
            #pragma unroll
            for (int j = 0; j < 4; j++)
                acc[i][j] = __builtin_amdgcn_mfma_f32_16x16x32_bf16(af[i], bv[j], acc[i][j], 0, 0, 0);
        __syncthreads();
    }
    const int er = (lane >> 4) * 4, ec = lane & 15;
    #pragma unroll
    for (int i = 0; i < IT; i++)
        #pragma unroll
        for (int j = 0; j < 4; j++)
            #pragma unroll
            for (int r = 0; r < 4; r++) {
                const int gm = m0 + wm + i * 16 + er + r;
                const int gn = n0 + wn + j * 16 + ec;
                const float v = acc[i][j][r];
                if constexpr (EPI == EPI_COMB) {
                    ((float*)C)[(long)zl * sCz + (long)gm * ldc + gn] =
                        (mask[(z >> 4) * T_ + gn] > 0) ? v : 0.0f;
                } else if constexpr (EPI == EPI_F32_BIAS) {
                    ((float*)C)[(long)gm * ldc + gn] = v + bias[gn];
                } else if constexpr (EPI == EPI_BF16_BIAS) {
                    ((u16*)C)[(long)gm * ldc + gn] = f2b(v + bias[gn]);
                } else {
                    ((u16*)C)[(long)gm * ldc + gn] = f2b(fmaxf(v + bias[gn], 0.0f));
                }
            }
}

// ---------------- repack V^T: Vt[s,z,d,t] = U/Vf[b*T+t, 2048+h*64+d] ----------------
__global__ __launch_bounds__(256) void repack_vt(const float* __restrict__ Uf,
                                                 const float* __restrict__ Vf,
                                                 u16* __restrict__ Vt) {
    __shared__ u16 Ts[64][65];
    int tid = threadIdx.x, tx = tid & 63, ty = tid >> 6;
    int t0 = blockIdx.x * 64;
    int sz = blockIdx.y, s = sz >> 5, z = sz & 31, b = z >> 4, h = z & 15;
    const float* srcp = s ? Vf : Uf;
    #pragma unroll
    for (int i = ty; i < 64; i += 4)
        Ts[i][tx] = f2b(srcp[(long)(b * T_ + t0 + i) * 3072 + 2048 + h * 64 + tx]);
    __syncthreads();
    u16* dst = Vt + (long)sz * HD_ * T_;
    #pragma unroll
    for (int i = ty; i < 64; i += 4) dst[(long)i * T_ + t0 + tx] = Ts[tx][i];
}

// ---- R/S partials: RSp[chunk][idx][d1*64+d2] = sum_{j in chunk} mask*k[j,d1]*q[j,d2]
__global__ __launch_bounds__(256) void rs_part(const float* __restrict__ Uf,
                                               const float* __restrict__ Vf,
                                               const int* __restrict__ smask,
                                               const int* __restrict__ amask,
                                               float* __restrict__ RSp) {
    __shared__ float Ksh[64 * 64];
    __shared__ float Qsh[64 * 64];
    int idx = blockIdx.x;
    int mat = idx >> 5, z = idx & 31, b = z >> 4, h = z & 15;
    int chunk = blockIdx.y, j0 = chunk * 64;
    const float* base = mat ? Uf : Vf;
    const int* mk = mat ? smask : amask;
    int tid = threadIdx.x;
    float4* K4 = (float4*)Ksh;
    float4* Q4 = (float4*)Qsh;
    for (int ii = tid; ii < 1024; ii += 256) {
        int j = ii >> 4, d4 = ii & 15;
        long row = (long)(b * T_ + j0 + j) * 3072 + h * 64;
        int m = mk[b * T_ + j0 + j];
        float4 kv = ((const float4*)&base[row + 1024])[d4];
        if (m <= 0) kv = (float4){0.f, 0.f, 0.f, 0.f};
        K4[ii] = kv;
        Q4[ii] = ((const float4*)&base[row])[d4];
    }
    __syncthreads();
    int d1 = tid >> 2, c0 = (tid & 3) * 16;
    float4 a[4];
    #pragma unroll
    for (int k = 0; k < 4; k++) a[k] = (float4){0.f, 0.f, 0.f, 0.f};
    for (int j = 0; j < 64; j++) {
        float kv = Ksh[j * 64 + d1];
        const float4* q = (const float4*)&Qsh[j * 64 + c0];
        #pragma unroll
        for (int k = 0; k < 4; k++) {
            float4 qv = q[k];
            a[k].x += kv * qv.x; a[k].y += kv * qv.y;
            a[k].z += kv * qv.z; a[k].w += kv * qv.w;
        }
    }
    float4* out = (float4*)&RSp[((long)chunk * 64 + idx) * 4096 + d1 * 64 + c0];
    #pragma unroll
    for (int k = 0; k < 4; k++) out[k] = a[k];
}

// ---- RS[idx][e] = sum_{chunk<16} RSp[chunk][idx][e]  (float4-wide) -----------------
__global__ __launch_bounds__(256) void rs_reduce(const float* __restrict__ RSp,
                                                 float* __restrict__ RS) {
    int gid = blockIdx.x * 256 + threadIdx.x;    // 65536 float4s
    const float4* in = (const float4*)RSp;
    float4 s = (float4){0.f, 0.f, 0.f, 0.f};
    #pragma unroll
    for (int c = 0; c < 16; c++) {
        float4 v = in[(long)c * 65536 + gid];
        s.x += v.x; s.y += v.y; s.z += v.z; s.w += v.w;
    }
    ((float4*)RS)[gid] = s;
}

// ---------------- Q' = (Q @ R)/64, hi/lo split to [qhi|qlo|qhi] (192) ----------------
__global__ __launch_bounds__(256) void qprime(const float* __restrict__ Uf,
                                              const float* __restrict__ Vf,
                                              const float* __restrict__ RS,
                                              u16* __restrict__ Qs) {
    __shared__ float Rm[4096];
    __shared__ float Qsh[128][65];
    int t0 = blockIdx.x * 128;
    int sz = blockIdx.y, s = sz >> 5, z = sz & 31, b = z >> 4, h = z & 15;
    const float* Qf = s ? Vf : Uf;
    const float* mat = RS + (long)(s * 32 + z) * 4096;
    int tid = threadIdx.x;
    for (int ii = tid; ii < 1024; ii += 256)
        ((float4*)Rm)[ii] = ((const float4*)mat)[ii];
    for (int ii = tid; ii < 2048; ii += 256) {
        int j = ii >> 4, d4 = ii & 15;
        float4 v = ((const float4*)&Qf[(long)(b * T_ + t0 + j) * 3072 + h * 64])[d4];
        Qsh[j][d4 * 4] = v.x; Qsh[j][d4 * 4 + 1] = v.y;
        Qsh[j][d4 * 4 + 2] = v.z; Qsh[j][d4 * 4 + 3] = v.w;
    }
    __syncthreads();
    int r = tid >> 1, c0 = (tid & 1) * 32;
    float4 acc[8];
    #pragma unroll
    for (int k = 0; k < 8; k++) acc[k] = (float4){0.f, 0.f, 0.f, 0.f};
    for (int d1 = 0; d1 < 64; d1++) {
        float q = Qsh[r][d1];
        const float4* rm = (const float4*)&Rm[d1 * 64 + c0];
        #pragma unroll
        for (int k = 0; k < 8; k++) {
            float4 rv = rm[k];
            acc[k].x += q * rv.x; acc[k].y += q * rv.y;
            acc[k].z += q * rv.z; acc[k].w += q * rv.w;
        }
    }
    u16* out = Qs + ((long)sz * T_ + (t0 + r)) * 192;
    #pragma unroll
    for (int k = 0; k < 8; k++) {
        #pragma unroll
        for (int e = 0; e < 4; e++) {
            float x = ((const float*)&acc[k])[e] * (1.f / 64.f);
            int c = k * 4 + e;
            u16 hi = f2b(x);
            u16 lo = f2b(x - b2f(hi));
            out[c0 + c] = hi;
            out[64 + c0 + c] = lo;
            out[128 + c0 + c] = hi;
        }
    }
}

// ---------------- K split to [khi|khi|klo] (192) ----------------
__global__ __launch_bounds__(256) void ksplit(const float* __restrict__ Uf,
                                              const float* __restrict__ Vf,
                                              u16* __restrict__ Ks) {
    int t0 = blockIdx.x * 128;
    int sz = blockIdx.y, s = sz >> 5, z = sz & 31, b = z >> 4, h = z & 15;
    const float* Kf = s ? Vf : Uf;
    int tid = threadIdx.x;
    int r = tid >> 1, c0 = (tid & 1) * 32;
    long krow = (long)(b * T_ + t0 + r) * 3072 + 1024 + h * 64;
    u16* out = Ks + ((long)sz * T_ + (t0 + r)) * 192;
    #pragma unroll
    for (int c = 0; c < 32; c++) {
        float x = Kf[krow + c0 + c];
        u16 hi = f2b(x);
        u16 lo = f2b(x - b2f(hi));
        out[c0 + c] = hi;
        out[64 + c0 + c] = hi;
        out[128 + c0 + c] = lo;
    }
}

// ---------------- row softmax: fp32 comb -> bf16 att ----------------
__global__ __launch_bounds__(256) void softmax_rows(const float* __restrict__ comb,
                                                    u16* __restrict__ att) {
    __shared__ float red[8];
    int row = blockIdx.x, zl = blockIdx.y;
    const float* src = comb + ((long)zl * T_ + row) * T_;
    u16* dst = att + ((long)zl * T_ + row) * T_;
    int tid = threadIdx.x, wave = tid >> 6, lane = tid & 63;
    float v0 = src[tid], v1 = src[tid + 256], v2 = src[tid + 512], v3 = src[tid + 768];
    float mx = fmaxf(fmaxf(v0, v1), fmaxf(v2, v3));
    mx = wred_max(mx);
    if (lane == 0) red[wave] = mx;
    __syncthreads();
    mx = fmaxf(fmaxf(red[0], red[1]), fmaxf(red[2], red[3]));
    v0 = __expf(v0 - mx); v1 = __expf(v1 - mx); v2 = __expf(v2 - mx); v3 = __expf(v3 - mx);
    float s = wred_sum(v0 + v1 + v2 + v3);
    if (lane == 0) red[4 + wave] = s;
    __syncthreads();
    s = red[4] + red[5] + red[6] + red[7];
    float inv = 1.f / s;
    dst[tid] = f2b(v0 * inv);
    dst[tid + 256] = f2b(v1 * inv);
    dst[tid + 512] = f2b(v2 * inv);
    dst[tid + 768] = f2b(v3 * inv);
}

// ------- PV: ctx[b*T+t, h*64+d] = att[zl] @ Vt[z]^T  (32x64 tile, 256-block grid) ---
__global__ __launch_bounds__(256) void attn_pv(const u16* __restrict__ att,
                                               const u16* __restrict__ Vt,
                                               u16* __restrict__ ctx, int zofs) {
    __shared__ u16 As[32 * 32];
    __shared__ u16 Bs[64 * 32];
    int tid = threadIdx.x, wave = tid >> 6, lane = tid & 63;
    int m0 = blockIdx.x * 32;
    int zl = blockIdx.y, z = zl + zofs, b = z >> 4, h = z & 15;
    const u16* Ab = att + (long)zl * T_ * T_;
    const u16* Bb = Vt + (long)z * HD_ * T_;
    int srow = lane >> 2, scol = (lane & 3) * 8;
    int rowstrip = (wave & 1) * 16, colbase = (wave >> 1) * 32;
    f32x4 acc[2];
    acc[0] = (f32x4){0.f, 0.f, 0.f, 0.f};
    acc[1] = (f32x4){0.f, 0.f, 0.f, 0.f};
    int fr = lane & 15, fk = (lane >> 4) * 8;
    for (int k0 = 0; k0 < T_; k0 += 32) {
        if (wave < 2)
            gl2lds16(Ab + (long)(m0 + wave * 16 + srow) * T_ + k0 + scol, &As[(wave * 16) * 32]);
        gl2lds16(Bb + (long)(wave * 16 + srow) * T_ + k0 + scol, &Bs[(wave * 16) * 32]);
        __syncthreads();
        bf16x8 af = *(const bf16x8*)&As[(rowstrip + fr) * 32 + fk];
        bf16x8 bv0 = *(const bf16x8*)&Bs[(colbase + fr) * 32 + fk];
        bf16x8 bv1 = *(const bf16x8*)&Bs[(colbase + 16 + fr) * 32 + fk];
        acc[0] = __builtin_amdgcn_mfma_f32_16x16x32_bf16(af, bv0, acc[0], 0, 0, 0);
        acc[1] = __builtin_amdgcn_mfma_f32_16x16x32_bf16(af, bv1, acc[1], 0, 0, 0);
        __syncthreads();
    }
    int er = (lane >> 4) * 4, ec = lane & 15;
    #pragma unroll
    for (int t = 0; t < 2; t++)
        #pragma unroll
        for (int r = 0; r < 4; r++) {
            int row = m0 + rowstrip + er + r;
            int col = colbase + t * 16 + ec;
            ctx[(long)(b * T_ + row) * D_ + h * 64 + col] = f2b(acc[t][r]);
        }
}

// ------- fused residual-add + LayerNorm: x f32-or-bf16, y bf16, out bf16-or-f32 -----
template <bool XF32, bool OUTF32>
__global__ __launch_bounds__(256) void ln_fused(const void* __restrict__ xp,
                                                const u16* __restrict__ y,
                                                const float* __restrict__ g,
                                                const float* __restrict__ be,
                                                void* __restrict__ out) {
    __shared__ float red[8];
    int row = blockIdx.x;
    long base = (long)row * 1024;
    int tid = threadIdx.x, wave = tid >> 6, lane = tid & 63;
    float v[4];
    #pragma unroll
    for (int i = 0; i < 4; i++) {
        int c = tid + i * 256;
        float xv = XF32 ? ((const float*)xp)[base + c] : b2f(((const u16*)xp)[base + c]);
        v[i] = xv + b2f(y[base + c]);
    }
    float s = v[0] + v[1] + v[2] + v[3];
    float q = v[0] * v[0] + v[1] * v[1] + v[2] * v[2] + v[3] * v[3];
    s = wred_sum(s);
    q = wred_sum(q);
    if (lane == 0) { red[wave] = s; red[4 + wave] = q; }
    __syncthreads();
    s = red[0] + red[1] + red[2] + red[3];
    q = red[4] + red[5] + red[6] + red[7];
    float mean = s * (1.f / 1024.f);
    float var = q * (1.f / 1024.f) - mean * mean;
    float inv = rsqrtf(var + 1e-5f);
    #pragma unroll
    for (int i = 0; i < 4; i++) {
        int c = tid + i * 256;
        float o = (v[i] - mean) * inv * g[c] + be[c];
        if (OUTF32) ((float*)out)[base + c] = o;
        else ((u16*)out)[base + c] = f2b(o);
    }
}

extern "C" void kernel_launch(void* const* d_in, const int* in_sizes, int n_in,
                              void* d_out, int out_size, void* d_ws, size_t ws_size,
                              hipStream_t stream) {
    const float* src = (const float*)d_in[0];
    const float* aux = (const float*)d_in[1];
    const float* Wu = (const float*)d_in[2];
    const float* bu = (const float*)d_in[3];
    const float* Wv = (const float*)d_in[4];
    const float* bv = (const float*)d_in[5];
    const float* Wo = (const float*)d_in[6];
    const float* bo = (const float*)d_in[7];
    const float* W1 = (const float*)d_in[8];
    const float* b1 = (const float*)d_in[9];
    const float* W2 = (const float*)d_in[10];
    const float* b2 = (const float*)d_in[11];
    const float* g1 = (const float*)d_in[12];
    const float* be1 = (const float*)d_in[13];
    const float* g2 = (const float*)d_in[14];
    const float* be2 = (const float*)d_in[15];
    const int* src_mask = (const int*)d_in[16];
    const int* aux_mask = (const int*)d_in[17];

    // -------- workspace (~159 MiB peak, time-phased; proven safe in R8) -------------
    char* w = (char*)d_ws;
    auto alloc = [&](size_t bytes) { char* p = w; w += (bytes + 255) & ~(size_t)255; return p; };
    // permanent (~75 MiB)
    u16* WoT = (u16*)alloc(1024L * 1024 * 2);
    u16* W1T = (u16*)alloc(4096L * 1024 * 2);
    u16* W2T = (u16*)alloc(1024L * 4096 * 2);
    u16* Vt  = (u16*)alloc(64L * 64 * 1024 * 2);
    float* RS = (float*)alloc(64L * 4096 * 4);
    u16* Qs = (u16*)alloc(64L * 1024 * 192 * 2);
    u16* Ks = (u16*)alloc(64L * 1024 * 192 * 2);
    // scratch union: 84 MiB, two time-phases
    char* scratch = (char*)alloc(84L * 1024 * 1024);
    // phase A: WS (split weight; later aliased by RSp after QKV gemms), As_, Uf, Vf
    u16* WS  = (u16*)(scratch);                        // 18874368
    float* RSp = (float*)(scratch);                    // 16777216 (aliases dead WS)
    u16* As_ = (u16*)(scratch + 18874368L);            // 12582912
    float* Uf = (float*)(scratch + 31457280L);         // 25165824
    float* Vf = (float*)(scratch + 56623104L);         // 25165824 (ends 81788928)
    // phase B: comb (8 z-slices), att, ctx, attn_s, o1s, hbuf, fbuf
    float* comb = (float*)(scratch);                   // 33554432
    u16* att    = (u16*)(scratch + 33554432L);         // 16777216
    u16* ctx    = (u16*)(scratch + 50331648L);         // 4194304
    u16* attn_s = (u16*)(scratch + 54525952L);         // 4194304
    u16* o1s    = (u16*)(scratch + 58720256L);         // 4194304
    u16* hbuf   = (u16*)(scratch + 62914560L);         // 16777216
    u16* fbuf   = (u16*)(scratch + 79691776L);         // 4194304 (ends 83886080)

    // -------- phase A: weight prep + hi/lo QKV projections + R/S + Q'/K splits ------
    transpose_cvt<<<dim3(16, 16), 256, 0, stream>>>(Wo, WoT, 1024, 1024);
    transpose_cvt<<<dim3(64, 16), 256, 0, stream>>>(W1, W1T, 1024, 4096);
    transpose_cvt<<<dim3(16, 64), 256, 0, stream>>>(W2, W2T, 4096, 1024);

    transpose_split<<<dim3(48, 16), 256, 0, stream>>>(Wu, WS, 1024, 3072);
    split_rows<<<2048, 256, 0, stream>>>(src, As_);
    gemm128<EPI_F32_BIAS, 128><<<dim3(16, 24, 1), 256, 0, stream>>>(
        As_, WS, Uf, bu, nullptr, 2048, 3072, 3072, 3072, 3072, 3072, 0, 0, 0, 0);
    transpose_split<<<dim3(48, 16), 256, 0, stream>>>(Wv, WS, 1024, 3072);
    split_rows<<<2048, 256, 0, stream>>>(aux, As_);
    gemm128<EPI_F32_BIAS, 128><<<dim3(16, 24, 1), 256, 0, stream>>>(
        As_, WS, Vf, bv, nullptr, 2048, 3072, 3072, 3072, 3072, 3072, 0, 0, 0, 0);
    // WS dead from here; RSp aliases it
    repack_vt<<<dim3(16, 64), 256, 0, stream>>>(Uf, Vf, Vt);
    rs_part<<<dim3(64, 16), 256, 0, stream>>>(Uf, Vf, src_mask, aux_mask, RSp);
    rs_reduce<<<256, 256, 0, stream>>>(RSp, RS);
    qprime<<<dim3(8, 64), 256, 0, stream>>>(Uf, Vf, RS, Qs);
    ksplit<<<dim3(8, 64), 256, 0, stream>>>(Uf, Vf, Ks);
    // ---- phase A scratch (WS/RSp/As_/Uf/Vf) dead; phase B overlays ------------------

    for (int s = 0; s < 2; s++) {
        const int* mk = s ? aux_mask : src_mask;
        const u16* Qsb = Qs + (long)s * 32 * 1024 * 192;
        const u16* Ksb = Ks + (long)s * 32 * 1024 * 192;
        for (int c = 0; c < 4; c++) {
            int zofs = c * 8;
            gemm128<EPI_COMB, 128><<<dim3(8, 8, 8), 256, 0, stream>>>(
                Qsb, Ksb, comb, nullptr, mk, 1024, 1024, 192, 192, 192, 1024,
                192L * 1024, 192L * 1024, 1024L * 1024, zofs);
            softmax_rows<<<dim3(1024, 8), 256, 0, stream>>>(comb, att);
            attn_pv<<<dim3(32, 8), 256, 0, stream>>>(att, Vt + (long)s * 32 * 64 * 1024, ctx, zofs);
        }
        gemm128<EPI_BF16_BIAS, 64><<<dim3(16, 16, 1), 256, 0, stream>>>(
            ctx, WoT, attn_s, bo, nullptr, 2048, 1024, 1024, 1024, 1024, 1024, 0, 0, 0, 0);
        const float* x = s ? aux : src;
        ln_fused<true, false><<<2048, 256, 0, stream>>>(x, attn_s, g1, be1, o1s);
        gemm128<EPI_BF16_BIAS_RELU, 128><<<dim3(16, 32, 1), 256, 0, stream>>>(
            o1s, W1T, hbuf, b1, nullptr, 2048, 4096, 1024, 1024, 1024, 4096, 0, 0, 0, 0);
        gemm128<EPI_BF16_BIAS, 64><<<dim3(16, 16, 1), 256, 0, stream>>>(
            hbuf, W2T, fbuf, b2, nullptr, 2048, 1024, 4096, 4096, 4096, 1024, 0, 0, 0, 0);
        ln_fused<false, true><<<2048, 256, 0, stream>>>(o1s, fbuf, g2, be2,
                                                        (float*)d_out + (long)s * 2097152);
    }
}